// Round 2
// baseline (2640.474 us; speedup 1.0000x reference)
//
#include <hip/hip_runtime.h>
#include <hip/hip_bf16.h>

typedef __hip_bfloat16 bf16;

// Problem constants: B=4, S=1024, M=8, D=64, H=8, NF=32, HD=512
#define CB 4
#define CS 1024
#define CM 8
#define CD 64
#define CH 8
#define CNF 32
#define CHD 512

__device__ __forceinline__ float b2f(bf16 x) { return __bfloat162float(x); }
__device__ __forceinline__ float us2f(unsigned short u) {
    union { unsigned int i; float f; } v; v.i = ((unsigned int)u) << 16; return v.f;
}

// ---------------------------------------------------------------------------
// Kernel 1: F[h][e][f] = sum_d W[h*64+d][e] * freqs[h][d][f]  (q and k variants)
// grid: 16 blocks (which*8 + h), 256 threads
// ---------------------------------------------------------------------------
__global__ __launch_bounds__(256) void prep_F(const float* __restrict__ Wq,
                                              const float* __restrict__ Wk,
                                              const float* __restrict__ freqs,
                                              float* __restrict__ Fq,
                                              float* __restrict__ Fk) {
    int h = blockIdx.x & 7;
    int which = blockIdx.x >> 3;
    const float* W = which ? Wk : Wq;
    float* F = which ? Fk : Fq;
    int t = threadIdx.x;
    int f = t & 31, e0 = t >> 5;  // f in 0..31, e0 in 0..7
    for (int ei = 0; ei < 8; ++ei) {
        int e = ei * 8 + e0;
        float acc = 0.f;
        for (int d = 0; d < 64; ++d)
            acc += W[(h * 64 + d) * 64 + e] * freqs[(h * 64 + d) * 32 + f];
        F[h * 2048 + e * 32 + f] = acc;
    }
}

// ---------------------------------------------------------------------------
// Kernel 2: q_enc/k_enc[b][h][s][f2] (f2<32: cos, f2>=32: sin), softmax-weighted
// over m.  grid: B*S blocks, 256 threads (thread -> (h = t>>5, f = t&31))
// ---------------------------------------------------------------------------
__global__ __launch_bounds__(256) void encode(const float* __restrict__ qa_in,
                                              const float* __restrict__ ql,
                                              const float* __restrict__ ka_in,
                                              const float* __restrict__ kl,
                                              const float* __restrict__ Fq,
                                              const float* __restrict__ Fk,
                                              float* __restrict__ q_enc,
                                              float* __restrict__ k_enc) {
    int x = blockIdx.x;            // b*S + s
    int b = x >> 10, s = x & 1023;
    __shared__ float atq[8][64];
    __shared__ float atk[8][64];
    __shared__ float lwq[8], lwk[8];
    int t = threadIdx.x;
    for (int i = t; i < 512; i += 256) {
        atq[i >> 6][i & 63] = qa_in[x * 512 + i];
        atk[i >> 6][i & 63] = ka_in[x * 512 + i];
    }
    if (t < 8) lwq[t] = ql[x * 8 + t];
    else if (t < 16) lwk[t - 8] = kl[x * 8 + t - 8];
    __syncthreads();

    int h = t >> 5, f = t & 31;
    const float rs = 0.17677669529663687f;  // 1/sqrt(32)
    int obase = ((b * 8 + h) * 1024 + s) * 64;

    for (int which = 0; which < 2; ++which) {
        const float* F = which ? Fk : Fq;
        const float (*at)[64] = which ? atk : atq;
        const float* lw = which ? lwk : lwq;
        float* enc = which ? k_enc : q_enc;

        // softmax weights over m (redundant per thread, 8 elems)
        float wgt[8];
        float mx = -1e30f;
        #pragma unroll
        for (int m = 0; m < 8; ++m) mx = fmaxf(mx, lw[m]);
        float sm = 0.f;
        #pragma unroll
        for (int m = 0; m < 8; ++m) { wgt[m] = __expf(lw[m] - mx); sm += wgt[m]; }
        float inv = 1.f / sm;
        #pragma unroll
        for (int m = 0; m < 8; ++m) wgt[m] *= inv;

        float fr[64];
        #pragma unroll
        for (int e = 0; e < 64; ++e) fr[e] = F[h * 2048 + e * 32 + f];

        float zc = 0.f, zs = 0.f;
        #pragma unroll
        for (int m = 0; m < 8; ++m) {
            float p = 0.f;
            #pragma unroll
            for (int e = 0; e < 64; ++e) p += at[m][e] * fr[e];
            float sv, cv;
            __sincosf(p, &sv, &cv);
            zc += wgt[m] * cv;
            zs += wgt[m] * sv;
        }
        enc[obase + f] = zc * rs;
        enc[obase + 32 + f] = zs * rs;
    }
}

// ---------------------------------------------------------------------------
// Kernel 3: V[b][h][s][m*64+d] = sum_e v_atoms[b,s,m,e] * Wv[h*64+d, e]  (bf16)
// grid: B*S blocks, 256 threads
// ---------------------------------------------------------------------------
__global__ __launch_bounds__(256) void vproj(const float* __restrict__ va_in,
                                             const float* __restrict__ Wv,
                                             bf16* __restrict__ V) {
    int x = blockIdx.x; int b = x >> 10, s = x & 1023;
    __shared__ float atv[8][64];
    int t = threadIdx.x;
    for (int i = t; i < 512; i += 256) atv[i >> 6][i & 63] = va_in[x * 512 + i];
    __syncthreads();
    for (int rep = 0; rep < 2; ++rep) {
        int c = rep * 256 + t;        // c = h*64 + d
        int h = c >> 6, d = c & 63;
        float w[64];
        #pragma unroll
        for (int e = 0; e < 64; ++e) w[e] = Wv[c * 64 + e];
        int vb = ((b * 8 + h) * 1024 + s) * 512 + d;
        #pragma unroll
        for (int m = 0; m < 8; ++m) {
            float acc = 0.f;
            #pragma unroll
            for (int e = 0; e < 64; ++e) acc += atv[m][e] * w[e];
            V[vb + m * 64] = __float2bfloat16(acc);
        }
    }
}

// ---------------------------------------------------------------------------
// Kernel 4: attention.  grid (S/16, H, B), 256 threads = 4 waves.
// Per block: Q tile [16,64]; scores vs all 1024 k; softmax; P @ V[1024,512];
// write tmp[b][q][m][h][d] (bf16).
// LDS: Qs 4KB + Sc(bf16) 32KB + rowsum -> ~36KB, 4 blocks/CU.
// ---------------------------------------------------------------------------
__global__ __launch_bounds__(256) void attn_kern(const float* __restrict__ q_enc,
                                                 const float* __restrict__ k_enc,
                                                 const bf16* __restrict__ V,
                                                 bf16* __restrict__ tmp) {
    int qb = blockIdx.x, h = blockIdx.y, b = blockIdx.z;
    int bh = b * 8 + h;
    __shared__ float Qs[16][64];
    __shared__ bf16 Sc[16][1024];
    __shared__ float rowsum[16];
    int t = threadIdx.x;

    for (int i = t; i < 1024; i += 256)
        Qs[i >> 6][i & 63] = q_enc[(bh * 1024 + qb * 16 + (i >> 6)) * 64 + (i & 63)];
    __syncthreads();

    // ---- scores: each thread handles 4 k-columns, all 16 rows
    const float ascale = 0.125f;  // 1/sqrt(64)
    for (int kk = 0; kk < 4; ++kk) {
        int k = kk * 256 + t;
        const float4* kr4 = (const float4*)(k_enc + (bh * 1024 + k) * 64);
        float krg[64];
        #pragma unroll
        for (int e4 = 0; e4 < 16; ++e4) {
            float4 v4 = kr4[e4];
            krg[e4 * 4 + 0] = v4.x; krg[e4 * 4 + 1] = v4.y;
            krg[e4 * 4 + 2] = v4.z; krg[e4 * 4 + 3] = v4.w;
        }
        #pragma unroll
        for (int r = 0; r < 16; ++r) {
            float acc = 0.f;
            const float4* q4p = (const float4*)Qs[r];
            #pragma unroll
            for (int e4 = 0; e4 < 16; ++e4) {
                float4 q4 = q4p[e4];
                acc += krg[e4 * 4 + 0] * q4.x + krg[e4 * 4 + 1] * q4.y
                     + krg[e4 * 4 + 2] * q4.z + krg[e4 * 4 + 3] * q4.w;
            }
            Sc[r][k] = __float2bfloat16(acc * ascale);
        }
    }
    __syncthreads();

    // ---- softmax: wave w handles rows 4w..4w+3
    int w = t >> 6, l = t & 63;
    for (int i = 0; i < 4; ++i) {
        int r = w * 4 + i;
        float mx = -1e30f;
        #pragma unroll
        for (int j = 0; j < 16; ++j) mx = fmaxf(mx, b2f(Sc[r][j * 64 + l]));
        #pragma unroll
        for (int off = 32; off; off >>= 1) mx = fmaxf(mx, __shfl_xor(mx, off));
        float sm = 0.f;
        #pragma unroll
        for (int j = 0; j < 16; ++j) {
            float e = __expf(b2f(Sc[r][j * 64 + l]) - mx);
            bf16 eb = __float2bfloat16(e);
            Sc[r][j * 64 + l] = eb;
            sm += b2f(eb);
        }
        #pragma unroll
        for (int off = 32; off; off >>= 1) sm += __shfl_xor(sm, off);
        if (l == 0) rowsum[r] = sm;
    }
    __syncthreads();

    // ---- P @ V : wave w -> rows 4w..4w+3, lane l -> V cols l*8 .. l*8+7
    float acc[4][8];
    #pragma unroll
    for (int i = 0; i < 4; ++i)
        #pragma unroll
        for (int j = 0; j < 8; ++j) acc[i][j] = 0.f;

    const bf16* vbase = V + bh * 1024 * 512 + l * 8;
    for (int k = 0; k < 1024; ++k) {
        uint4 vv = *((const uint4*)(vbase + k * 512));
        const unsigned short* us = (const unsigned short*)&vv;
        float vf[8];
        #pragma unroll
        for (int j = 0; j < 8; ++j) vf[j] = us2f(us[j]);
        #pragma unroll
        for (int i = 0; i < 4; ++i) {
            float p = b2f(Sc[w * 4 + i][k]);
            #pragma unroll
            for (int j = 0; j < 8; ++j) acc[i][j] += p * vf[j];
        }
    }

    int m = l >> 3, d0 = (l & 7) * 8;
    for (int i = 0; i < 4; ++i) {
        int r = w * 4 + i;
        int q = qb * 16 + r;
        float inv = 1.f / rowsum[r];
        union { bf16 ob[8]; uint4 u; } pk;
        #pragma unroll
        for (int j = 0; j < 8; ++j) pk.ob[j] = __float2bfloat16(acc[i][j] * inv);
        *((uint4*)(tmp + ((((b * 1024 + q) * 8 + m) * 8 + h) * 64 + d0))) = pk.u;
    }
}

// ---------------------------------------------------------------------------
// Kernel 5: out_atoms = tmp @ Wo^T ; feat = mean_m ; new_logw = q_logw + feat@Ww^T
// grid: B*S blocks, 256 threads
// ---------------------------------------------------------------------------
__global__ __launch_bounds__(256) void finalize(const bf16* __restrict__ tmp,
                                                const float* __restrict__ Wo,
                                                const float* __restrict__ Ww,
                                                const float* __restrict__ ql,
                                                float* __restrict__ out) {
    int x = blockIdx.x;  // b*S + s
    __shared__ float tm[8][512];   // 16KB
    __shared__ float outv[8][64];
    __shared__ float feat[64];
    __shared__ float lw[8];
    int t = threadIdx.x;
    // load tmp[b,s] : 4096 bf16 as 512 x uint4 chunks
    for (int rep = 0; rep < 2; ++rep) {
        int ch = rep * 256 + t;    // chunk id 0..511 ; m = ch>>6, c0 = (ch&63)*8
        uint4 v = ((const uint4*)(tmp + x * 4096))[ch];
        const unsigned short* us = (const unsigned short*)&v;
        #pragma unroll
        for (int j = 0; j < 8; ++j) tm[ch >> 6][(ch & 63) * 8 + j] = us2f(us[j]);
    }
    if (t < 8) lw[t] = ql[x * 8 + t];
    __syncthreads();

    int w = t >> 6, o = t & 63;
    for (int rep = 0; rep < 2; ++rep) {
        int m = w + rep * 4;
        float acc = 0.f;
        for (int c0 = 0; c0 < 512; c0 += 4) {
            float4 wv = *((const float4*)(Wo + o * 512 + c0));
            acc += tm[m][c0 + 0] * wv.x + tm[m][c0 + 1] * wv.y
                 + tm[m][c0 + 2] * wv.z + tm[m][c0 + 3] * wv.w;
        }
        outv[m][o] = acc;
        out[(x * 8 + m) * 64 + o] = acc;
    }
    __syncthreads();
    if (t < 64) {
        float f = 0.f;
        #pragma unroll
        for (int m = 0; m < 8; ++m) f += outv[m][t];
        feat[t] = f * 0.125f;
    }
    __syncthreads();
    if (t < 8) {
        float nl = lw[t];
        for (int o2 = 0; o2 < 64; ++o2) nl += feat[o2] * Ww[t * 64 + o2];
        out[CB * CS * CM * CD + x * 8 + t] = nl;
    }
}

// ---------------------------------------------------------------------------
extern "C" void kernel_launch(void* const* d_in, const int* in_sizes, int n_in,
                              void* d_out, int out_size, void* d_ws, size_t ws_size,
                              hipStream_t stream) {
    const float* q_atoms = (const float*)d_in[0];
    const float* q_logw  = (const float*)d_in[1];
    const float* k_atoms = (const float*)d_in[2];
    const float* k_logw  = (const float*)d_in[3];
    const float* v_atoms = (const float*)d_in[4];
    // d_in[5] = v_logw (unused by the reference)
    const float* Wq = (const float*)d_in[6];
    const float* Wk = (const float*)d_in[7];
    const float* Wv = (const float*)d_in[8];
    const float* Wo = (const float*)d_in[9];
    const float* Ww = (const float*)d_in[10];
    const float* freqs = (const float*)d_in[11];

    // workspace layout (floats unless noted):
    //   Fq[16384] | Fk[16384] | q_enc[2097152] | k_enc[2097152]
    //   | V bf16[16777216] | tmp bf16[16777216]   (~80 MB total)
    float* ws = (float*)d_ws;
    float* Fq = ws;
    float* Fk = ws + 16384;
    float* q_enc = ws + 32768;
    float* k_enc = q_enc + 2097152;
    bf16* V = (bf16*)(k_enc + 2097152);
    bf16* tmp = V + 16777216;
    float* out = (float*)d_out;

    prep_F<<<16, 256, 0, stream>>>(Wq, Wk, freqs, Fq, Fk);
    encode<<<CB * CS, 256, 0, stream>>>(q_atoms, q_logw, k_atoms, k_logw,
                                        Fq, Fk, q_enc, k_enc);
    vproj<<<CB * CS, 256, 0, stream>>>(v_atoms, Wv, V);
    attn_kern<<<dim3(CS / 16, CH, CB), 256, 0, stream>>>(q_enc, k_enc, V, tmp);
    finalize<<<CB * CS, 256, 0, stream>>>(tmp, Wo, Ww, q_logw, out);
}

// Round 3
// 1147.679 us; speedup vs baseline: 2.3007x; 2.3007x over previous
//
#include <hip/hip_runtime.h>
#include <hip/hip_bf16.h>

typedef __hip_bfloat16 bf16;
typedef __attribute__((ext_vector_type(8))) short short8;
typedef __attribute__((ext_vector_type(4))) float floatx4;

// Problem constants: B=4, S=1024, M=8, D=64, H=8, NF=32, HD=512
#define CB 4
#define CS 1024
#define CM 8
#define CD 64
#define CH 8
#define CNF 32
#define CHD 512

#define SC_STRIDE 1056   // score-row stride (bf16): 16B-aligned rows, even bank spread
#define OB_STRIDE 520    // epilogue staging stride (bf16): 16B-aligned rows

__device__ __forceinline__ float b2f(bf16 x) { return __bfloat162float(x); }
__device__ __forceinline__ float us2f(unsigned short u) {
    union { unsigned int i; float f; } v; v.i = ((unsigned int)u) << 16; return v.f;
}
__device__ __forceinline__ floatx4 mfma16(short8 a, short8 b, floatx4 c) {
    return __builtin_amdgcn_mfma_f32_16x16x32_bf16(a, b, c, 0, 0, 0);
}

// ---------------------------------------------------------------------------
// Kernel 1: F[h][e][f] = sum_d W[h*64+d][e] * freqs[h][d][f]  (q and k variants)
// ---------------------------------------------------------------------------
__global__ __launch_bounds__(256) void prep_F(const float* __restrict__ Wq,
                                              const float* __restrict__ Wk,
                                              const float* __restrict__ freqs,
                                              float* __restrict__ Fq,
                                              float* __restrict__ Fk) {
    int h = blockIdx.x & 7;
    int which = blockIdx.x >> 3;
    const float* W = which ? Wk : Wq;
    float* F = which ? Fk : Fq;
    int t = threadIdx.x;
    int f = t & 31, e0 = t >> 5;
    for (int ei = 0; ei < 8; ++ei) {
        int e = ei * 8 + e0;
        float acc = 0.f;
        for (int d = 0; d < 64; ++d)
            acc += W[(h * 64 + d) * 64 + e] * freqs[(h * 64 + d) * 32 + f];
        F[h * 2048 + e * 32 + f] = acc;
    }
}

// ---------------------------------------------------------------------------
// Kernel 2: q_enc/k_enc[bh][s][f2] (f2<32: cos, f2>=32: sin), softmax-weighted
// over m.  Output bf16.  grid: B*S blocks, 256 threads (h = t>>5, f = t&31)
// ---------------------------------------------------------------------------
__global__ __launch_bounds__(256) void encode(const float* __restrict__ qa_in,
                                              const float* __restrict__ ql,
                                              const float* __restrict__ ka_in,
                                              const float* __restrict__ kl,
                                              const float* __restrict__ Fq,
                                              const float* __restrict__ Fk,
                                              bf16* __restrict__ q_enc,
                                              bf16* __restrict__ k_enc) {
    int x = blockIdx.x;            // b*S + s
    int b = x >> 10, s = x & 1023;
    __shared__ float atq[8][64];
    __shared__ float atk[8][64];
    __shared__ float lwq[8], lwk[8];
    int t = threadIdx.x;
    for (int i = t; i < 512; i += 256) {
        atq[i >> 6][i & 63] = qa_in[x * 512 + i];
        atk[i >> 6][i & 63] = ka_in[x * 512 + i];
    }
    if (t < 8) lwq[t] = ql[x * 8 + t];
    else if (t < 16) lwk[t - 8] = kl[x * 8 + t - 8];
    __syncthreads();

    int h = t >> 5, f = t & 31;
    const float rs = 0.17677669529663687f;  // 1/sqrt(32)
    int obase = ((b * 8 + h) * 1024 + s) * 64;

    for (int which = 0; which < 2; ++which) {
        const float* F = which ? Fk : Fq;
        const float (*at)[64] = which ? atk : atq;
        const float* lw = which ? lwk : lwq;
        bf16* enc = which ? k_enc : q_enc;

        float wgt[8];
        float mx = -1e30f;
        #pragma unroll
        for (int m = 0; m < 8; ++m) mx = fmaxf(mx, lw[m]);
        float sm = 0.f;
        #pragma unroll
        for (int m = 0; m < 8; ++m) { wgt[m] = __expf(lw[m] - mx); sm += wgt[m]; }
        float inv = 1.f / sm;
        #pragma unroll
        for (int m = 0; m < 8; ++m) wgt[m] *= inv;

        float fr[64];
        #pragma unroll
        for (int e = 0; e < 64; ++e) fr[e] = F[h * 2048 + e * 32 + f];

        float zc = 0.f, zs = 0.f;
        #pragma unroll
        for (int m = 0; m < 8; ++m) {
            float p = 0.f;
            #pragma unroll
            for (int e = 0; e < 64; ++e) p += at[m][e] * fr[e];
            float sv, cv;
            __sincosf(p, &sv, &cv);
            zc += wgt[m] * cv;
            zs += wgt[m] * sv;
        }
        enc[obase + f] = __float2bfloat16(zc * rs);
        enc[obase + 32 + f] = __float2bfloat16(zs * rs);
    }
}

// ---------------------------------------------------------------------------
// Kernel 3: Vt[bh][n][k] (n = m*64+d, k = s), bf16, n-major for MFMA B-frags.
// grid: B*(S/8) = 512 blocks, 256 threads; each block: 8 s-values, all (h,n).
// ---------------------------------------------------------------------------
__global__ __launch_bounds__(256) void vproj(const float* __restrict__ va_in,
                                             const float* __restrict__ Wv,
                                             bf16* __restrict__ Vt) {
    int x = blockIdx.x;
    int b = x >> 7, s0 = (x & 127) * 8;
    __shared__ float atv[8][64][8];   // [m][e][si] 16KB — si contiguous
    int t = threadIdx.x;
    const float* src = va_in + ((size_t)(b * 1024 + s0)) * 512;
    #pragma unroll
    for (int i = 0; i < 4; ++i) {
        int idx4 = t + 256 * i;           // float4 id, 1024 total
        float4 v4 = ((const float4*)src)[idx4];
        int flat = idx4 * 4;              // si*512 + m*64 + e
        int si = flat >> 9, m = (flat >> 6) & 7, e = flat & 63;
        atv[m][e + 0][si] = v4.x;
        atv[m][e + 1][si] = v4.y;
        atv[m][e + 2][si] = v4.z;
        atv[m][e + 3][si] = v4.w;
    }
    __syncthreads();
    for (int rep = 0; rep < 2; ++rep) {
        int c = rep * 256 + t;            // h*64 + d
        int h = c >> 6, d = c & 63;
        float w[64];
        #pragma unroll
        for (int e4 = 0; e4 < 16; ++e4) {
            float4 wv = ((const float4*)(Wv + c * 64))[e4];
            w[e4 * 4 + 0] = wv.x; w[e4 * 4 + 1] = wv.y;
            w[e4 * 4 + 2] = wv.z; w[e4 * 4 + 3] = wv.w;
        }
        for (int m = 0; m < 8; ++m) {
            float acc[8] = {0, 0, 0, 0, 0, 0, 0, 0};
            for (int e = 0; e < 64; ++e) {
                float we = w[e];
                const float4 p0 = *(const float4*)&atv[m][e][0];
                const float4 p1 = *(const float4*)&atv[m][e][4];
                acc[0] += p0.x * we; acc[1] += p0.y * we;
                acc[2] += p0.z * we; acc[3] += p0.w * we;
                acc[4] += p1.x * we; acc[5] += p1.y * we;
                acc[6] += p1.z * we; acc[7] += p1.w * we;
            }
            union { bf16 ob[8]; uint4 u; } pk;
            #pragma unroll
            for (int si = 0; si < 8; ++si) pk.ob[si] = __float2bfloat16(acc[si]);
            *(uint4*)(Vt + ((size_t)((b * 8 + h) * 512 + m * 64 + d)) * 1024 + s0) = pk.u;
        }
    }
}

// ---------------------------------------------------------------------------
// Kernel 4: attention via MFMA.  grid (S/16, H, B), 256 threads = 4 waves.
// QK^T (MFMA) -> Sc LDS -> softmax -> P@V (MFMA, Vt n-major) -> coalesced out.
// ---------------------------------------------------------------------------
__global__ __launch_bounds__(256) void attn_kern(const bf16* __restrict__ q_enc,
                                                 const bf16* __restrict__ k_enc,
                                                 const bf16* __restrict__ Vt,
                                                 bf16* __restrict__ tmp) {
    int qb = blockIdx.x, h = blockIdx.y, b = blockIdx.z;
    int bh = b * 8 + h;
    __shared__ __align__(16) bf16 Sc[16][SC_STRIDE];
    __shared__ float rowsum[16];
    int t = threadIdx.x;
    int w = t >> 6, l = t & 63;
    int quad = l >> 4, r = l & 15;

    // Q A-fragments (A[m=r][k=quad*8+j]); same for all waves
    const bf16* qrow = q_enc + ((size_t)(bh * 1024 + qb * 16 + r)) * 64 + quad * 8;
    short8 a0 = *(const short8*)(qrow);
    short8 a1 = *(const short8*)(qrow + 32);

    // ---- QK^T: wave w handles k-tiles w*16 .. w*16+15
    const float ascale = 0.125f;  // 1/sqrt(64)
    for (int i = 0; i < 16; ++i) {
        int kt = w * 16 + i;
        const bf16* krow = k_enc + ((size_t)(bh * 1024 + kt * 16 + r)) * 64 + quad * 8;
        short8 b0 = *(const short8*)(krow);
        short8 b1 = *(const short8*)(krow + 32);
        floatx4 c = {0.f, 0.f, 0.f, 0.f};
        c = mfma16(a0, b0, c);
        c = mfma16(a1, b1, c);
        #pragma unroll
        for (int reg = 0; reg < 4; ++reg)
            Sc[quad * 4 + reg][kt * 16 + r] = __float2bfloat16(c[reg] * ascale);
    }
    __syncthreads();

    // ---- softmax: wave w handles rows 4w..4w+3 (exp kept unnormalized in Sc)
    for (int i = 0; i < 4; ++i) {
        int row = w * 4 + i;
        float mx = -1e30f;
        #pragma unroll
        for (int j = 0; j < 16; ++j) mx = fmaxf(mx, b2f(Sc[row][j * 64 + l]));
        #pragma unroll
        for (int off = 32; off; off >>= 1) mx = fmaxf(mx, __shfl_xor(mx, off));
        float sm = 0.f;
        #pragma unroll
        for (int j = 0; j < 16; ++j) {
            float e = __expf(b2f(Sc[row][j * 64 + l]) - mx);
            bf16 eb = __float2bfloat16(e);
            Sc[row][j * 64 + l] = eb;
            sm += b2f(eb);
        }
        #pragma unroll
        for (int off = 32; off; off >>= 1) sm += __shfl_xor(sm, off);
        if (l == 0) rowsum[row] = sm;
    }
    __syncthreads();

    // ---- P@V: wave w owns n-range [w*128, w*128+128) = 8 n-tiles of 16
    floatx4 acc[8];
    #pragma unroll
    for (int nt = 0; nt < 8; ++nt) acc[nt] = (floatx4){0.f, 0.f, 0.f, 0.f};

    const bf16* vb = Vt + ((size_t)(bh * 512 + w * 128 + r)) * 1024 + quad * 8;
    for (int ks = 0; ks < 32; ++ks) {
        short8 a = *(const short8*)(&Sc[r][ks * 32 + quad * 8]);
        #pragma unroll
        for (int nt = 0; nt < 8; ++nt) {
            short8 bf = *(const short8*)(vb + nt * 16384 + ks * 32);
            acc[nt] = mfma16(a, bf, acc[nt]);
        }
    }
    __syncthreads();   // all Sc reads done; reuse Sc space for output staging

    bf16* Ob = &Sc[0][0];
    float inv[4];
    #pragma unroll
    for (int reg = 0; reg < 4; ++reg) inv[reg] = 1.f / rowsum[quad * 4 + reg];
    #pragma unroll
    for (int nt = 0; nt < 8; ++nt)
        #pragma unroll
        for (int reg = 0; reg < 4; ++reg)
            Ob[(quad * 4 + reg) * OB_STRIDE + w * 128 + nt * 16 + r] =
                __float2bfloat16(acc[nt][reg] * inv[reg]);
    __syncthreads();

    // coalesced store: 16 rows x 512 cols bf16 -> tmp[b][q][m][h][d]
    #pragma unroll
    for (int i = 0; i < 4; ++i) {
        int c = i * 256 + t;          // 0..1023 chunks of 8 bf16
        int row = c >> 6, j = c & 63;
        int m = j >> 3, d0 = (j & 7) * 8;
        short8 v = *(const short8*)(Ob + row * OB_STRIDE + j * 8);
        *(short8*)(tmp + ((((size_t)(b * 1024 + qb * 16 + row) * 8 + m) * 8 + h) * 64 + d0)) = v;
    }
}

// ---------------------------------------------------------------------------
// Kernel 5: out_atoms = tmp @ Wo^T ; feat = mean_m ; new_logw = q_logw + feat@Ww^T
// ---------------------------------------------------------------------------
__global__ __launch_bounds__(256) void finalize(const bf16* __restrict__ tmp,
                                                const float* __restrict__ Wo,
                                                const float* __restrict__ Ww,
                                                const float* __restrict__ ql,
                                                float* __restrict__ out) {
    int x = blockIdx.x;  // b*S + s
    __shared__ float tm[8][512];
    __shared__ float outv[8][64];
    __shared__ float feat[64];
    __shared__ float lw[8];
    int t = threadIdx.x;
    for (int rep = 0; rep < 2; ++rep) {
        int ch = rep * 256 + t;
        uint4 v = ((const uint4*)(tmp + (size_t)x * 4096))[ch];
        const unsigned short* us = (const unsigned short*)&v;
        #pragma unroll
        for (int j = 0; j < 8; ++j) tm[ch >> 6][(ch & 63) * 8 + j] = us2f(us[j]);
    }
    if (t < 8) lw[t] = ql[x * 8 + t];
    __syncthreads();

    int w = t >> 6, o = t & 63;
    for (int rep = 0; rep < 2; ++rep) {
        int m = w + rep * 4;
        float acc = 0.f;
        for (int c0 = 0; c0 < 512; c0 += 4) {
            float4 wv = *((const float4*)(Wo + o * 512 + c0));
            acc += tm[m][c0 + 0] * wv.x + tm[m][c0 + 1] * wv.y
                 + tm[m][c0 + 2] * wv.z + tm[m][c0 + 3] * wv.w;
        }
        outv[m][o] = acc;
        out[((size_t)x * 8 + m) * 64 + o] = acc;
    }
    __syncthreads();
    if (t < 64) {
        float f = 0.f;
        #pragma unroll
        for (int m = 0; m < 8; ++m) f += outv[m][t];
        feat[t] = f * 0.125f;
    }
    __syncthreads();
    if (t < 8) {
        float nl = lw[t];
        for (int o2 = 0; o2 < 64; ++o2) nl += feat[o2] * Ww[t * 64 + o2];
        out[CB * CS * CM * CD + x * 8 + t] = nl;
    }
}

// ---------------------------------------------------------------------------
extern "C" void kernel_launch(void* const* d_in, const int* in_sizes, int n_in,
                              void* d_out, int out_size, void* d_ws, size_t ws_size,
                              hipStream_t stream) {
    const float* q_atoms = (const float*)d_in[0];
    const float* q_logw  = (const float*)d_in[1];
    const float* k_atoms = (const float*)d_in[2];
    const float* k_logw  = (const float*)d_in[3];
    const float* v_atoms = (const float*)d_in[4];
    // d_in[5] = v_logw (unused by the reference)
    const float* Wq = (const float*)d_in[6];
    const float* Wk = (const float*)d_in[7];
    const float* Wv = (const float*)d_in[8];
    const float* Wo = (const float*)d_in[9];
    const float* Ww = (const float*)d_in[10];
    const float* freqs = (const float*)d_in[11];

    // ws layout: Fq fp32[16384] | Fk fp32[16384] | q_enc bf16[2097152]
    //            | k_enc bf16[2097152] | Vt bf16[16777216] | tmp bf16[16777216]
    // ~72.1 MB total
    float* ws = (float*)d_ws;
    float* Fq = ws;
    float* Fk = ws + 16384;
    bf16* q_enc = (bf16*)(ws + 32768);
    bf16* k_enc = q_enc + 2097152;
    bf16* Vt = k_enc + 2097152;
    bf16* tmp = Vt + 16777216;
    float* out = (float*)d_out;

    prep_F<<<16, 256, 0, stream>>>(Wq, Wk, freqs, Fq, Fk);
    encode<<<CB * CS, 256, 0, stream>>>(q_atoms, q_logw, k_atoms, k_logw,
                                        Fq, Fk, q_enc, k_enc);
    vproj<<<CB * CS / 8, 256, 0, stream>>>(v_atoms, Wv, Vt);
    attn_kern<<<dim3(CS / 16, CH, CB), 256, 0, stream>>>(q_enc, k_enc, Vt, tmp);
    finalize<<<CB * CS, 256, 0, stream>>>(tmp, Wo, Ww, q_logw, out);
}

// Round 4
// 722.553 us; speedup vs baseline: 3.6544x; 1.5884x over previous
//
#include <hip/hip_runtime.h>
#include <hip/hip_bf16.h>

typedef __hip_bfloat16 bf16;
typedef __attribute__((ext_vector_type(8))) short short8;
typedef __attribute__((ext_vector_type(4))) float floatx4;

// Problem constants: B=4, S=1024, M=8, D=64, H=8, NF=32, HD=512
#define CB 4
#define CS 1024
#define CM 8
#define CD 64
#define CH 8
#define CNF 32
#define CHD 512

#define SC_STRIDE 1056   // score-row stride (bf16): 16B-aligned rows, even bank spread
#define OB_STRIDE 520    // epilogue staging stride (bf16): 16B-aligned rows
#define OS_STRIDE 68     // finalize staging stride (fp32): 16B-aligned, +4 bank rotate/row

__device__ __forceinline__ float b2f(bf16 x) { return __bfloat162float(x); }
__device__ __forceinline__ float us2f(unsigned short u) {
    union { unsigned int i; float f; } v; v.i = ((unsigned int)u) << 16; return v.f;
}
__device__ __forceinline__ floatx4 mfma16(short8 a, short8 b, floatx4 c) {
    return __builtin_amdgcn_mfma_f32_16x16x32_bf16(a, b, c, 0, 0, 0);
}

// ---------------------------------------------------------------------------
// Kernel 1: F[h][e][f] = sum_d W[h*64+d][e] * freqs[h][d][f]  (q and k variants)
// + convert Wo (fp32[64][512]) -> bf16 Wo_bf
// ---------------------------------------------------------------------------
__global__ __launch_bounds__(256) void prep_F(const float* __restrict__ Wq,
                                              const float* __restrict__ Wk,
                                              const float* __restrict__ freqs,
                                              const float* __restrict__ Wo,
                                              float* __restrict__ Fq,
                                              float* __restrict__ Fk,
                                              bf16* __restrict__ Wo_bf) {
    int h = blockIdx.x & 7;
    int which = blockIdx.x >> 3;
    const float* W = which ? Wk : Wq;
    float* F = which ? Fk : Fq;
    int t = threadIdx.x;
    int f = t & 31, e0 = t >> 5;
    for (int ei = 0; ei < 8; ++ei) {
        int e = ei * 8 + e0;
        float acc = 0.f;
        for (int d = 0; d < 64; ++d)
            acc += W[(h * 64 + d) * 64 + e] * freqs[(h * 64 + d) * 32 + f];
        F[h * 2048 + e * 32 + f] = acc;
    }
    // Wo -> bf16: 32768 elems, 4096 threads x 2 float4
    int gid = blockIdx.x * 256 + t;
    #pragma unroll
    for (int i = 0; i < 2; ++i) {
        int idx4 = gid * 2 + i;
        float4 v = ((const float4*)Wo)[idx4];
        union { bf16 ob[4]; uint2 u; } pk;
        pk.ob[0] = __float2bfloat16(v.x); pk.ob[1] = __float2bfloat16(v.y);
        pk.ob[2] = __float2bfloat16(v.z); pk.ob[3] = __float2bfloat16(v.w);
        *(uint2*)(Wo_bf + idx4 * 4) = pk.u;
    }
}

// ---------------------------------------------------------------------------
// Kernel 2: q_enc/k_enc[bh][s][f2] (f2<32: cos, f2>=32: sin), softmax-weighted
// over m.  Output bf16.  grid: B*S blocks, 256 threads (h = t>>5, f = t&31)
// ---------------------------------------------------------------------------
__global__ __launch_bounds__(256) void encode(const float* __restrict__ qa_in,
                                              const float* __restrict__ ql,
                                              const float* __restrict__ ka_in,
                                              const float* __restrict__ kl,
                                              const float* __restrict__ Fq,
                                              const float* __restrict__ Fk,
                                              bf16* __restrict__ q_enc,
                                              bf16* __restrict__ k_enc) {
    int x = blockIdx.x;            // b*S + s
    int b = x >> 10, s = x & 1023;
    __shared__ float atq[8][64];
    __shared__ float atk[8][64];
    __shared__ float lwq[8], lwk[8];
    int t = threadIdx.x;
    for (int i = t; i < 512; i += 256) {
        atq[i >> 6][i & 63] = qa_in[x * 512 + i];
        atk[i >> 6][i & 63] = ka_in[x * 512 + i];
    }
    if (t < 8) lwq[t] = ql[x * 8 + t];
    else if (t < 16) lwk[t - 8] = kl[x * 8 + t - 8];
    __syncthreads();

    int h = t >> 5, f = t & 31;
    const float rs = 0.17677669529663687f;  // 1/sqrt(32)
    int obase = ((b * 8 + h) * 1024 + s) * 64;

    for (int which = 0; which < 2; ++which) {
        const float* F = which ? Fk : Fq;
        const float (*at)[64] = which ? atk : atq;
        const float* lw = which ? lwk : lwq;
        bf16* enc = which ? k_enc : q_enc;

        float wgt[8];
        float mx = -1e30f;
        #pragma unroll
        for (int m = 0; m < 8; ++m) mx = fmaxf(mx, lw[m]);
        float sm = 0.f;
        #pragma unroll
        for (int m = 0; m < 8; ++m) { wgt[m] = __expf(lw[m] - mx); sm += wgt[m]; }
        float inv = 1.f / sm;
        #pragma unroll
        for (int m = 0; m < 8; ++m) wgt[m] *= inv;

        float fr[64];
        #pragma unroll
        for (int e = 0; e < 64; ++e) fr[e] = F[h * 2048 + e * 32 + f];

        float zc = 0.f, zs = 0.f;
        #pragma unroll
        for (int m = 0; m < 8; ++m) {
            float p = 0.f;
            #pragma unroll
            for (int e = 0; e < 64; ++e) p += at[m][e] * fr[e];
            float sv, cv;
            __sincosf(p, &sv, &cv);
            zc += wgt[m] * cv;
            zs += wgt[m] * sv;
        }
        enc[obase + f] = __float2bfloat16(zc * rs);
        enc[obase + 32 + f] = __float2bfloat16(zs * rs);
    }
}

// ---------------------------------------------------------------------------
// Kernel 3: Vt[bh][n][k] (n = m*64+d, k = s), bf16, n-major for MFMA B-frags.
// grid: B*(S/8) = 512 blocks, 256 threads; each block: 8 s-values, all (h,n).
// ---------------------------------------------------------------------------
__global__ __launch_bounds__(256) void vproj(const float* __restrict__ va_in,
                                             const float* __restrict__ Wv,
                                             bf16* __restrict__ Vt) {
    int x = blockIdx.x;
    int b = x >> 7, s0 = (x & 127) * 8;
    __shared__ float atv[8][64][8];   // [m][e][si] 16KB — si contiguous
    int t = threadIdx.x;
    const float* src = va_in + ((size_t)(b * 1024 + s0)) * 512;
    #pragma unroll
    for (int i = 0; i < 4; ++i) {
        int idx4 = t + 256 * i;           // float4 id, 1024 total
        float4 v4 = ((const float4*)src)[idx4];
        int flat = idx4 * 4;              // si*512 + m*64 + e
        int si = flat >> 9, m = (flat >> 6) & 7, e = flat & 63;
        atv[m][e + 0][si] = v4.x;
        atv[m][e + 1][si] = v4.y;
        atv[m][e + 2][si] = v4.z;
        atv[m][e + 3][si] = v4.w;
    }
    __syncthreads();
    for (int rep = 0; rep < 2; ++rep) {
        int c = rep * 256 + t;            // h*64 + d
        int h = c >> 6, d = c & 63;
        float w[64];
        #pragma unroll
        for (int e4 = 0; e4 < 16; ++e4) {
            float4 wv = ((const float4*)(Wv + c * 64))[e4];
            w[e4 * 4 + 0] = wv.x; w[e4 * 4 + 1] = wv.y;
            w[e4 * 4 + 2] = wv.z; w[e4 * 4 + 3] = wv.w;
        }
        for (int m = 0; m < 8; ++m) {
            float acc[8] = {0, 0, 0, 0, 0, 0, 0, 0};
            for (int e = 0; e < 64; ++e) {
                float we = w[e];
                const float4 p0 = *(const float4*)&atv[m][e][0];
                const float4 p1 = *(const float4*)&atv[m][e][4];
                acc[0] += p0.x * we; acc[1] += p0.y * we;
                acc[2] += p0.z * we; acc[3] += p0.w * we;
                acc[4] += p1.x * we; acc[5] += p1.y * we;
                acc[6] += p1.z * we; acc[7] += p1.w * we;
            }
            union { bf16 ob[8]; uint4 u; } pk;
            #pragma unroll
            for (int si = 0; si < 8; ++si) pk.ob[si] = __float2bfloat16(acc[si]);
            *(uint4*)(Vt + ((size_t)((b * 8 + h) * 512 + m * 64 + d)) * 1024 + s0) = pk.u;
        }
    }
}

// ---------------------------------------------------------------------------
// Kernel 4: attention via MFMA.  grid (S/16, H, B), 256 threads = 4 waves.
// QK^T (MFMA) -> Sc LDS -> softmax -> P@V (MFMA, Vt n-major) -> coalesced out.
// ---------------------------------------------------------------------------
__global__ __launch_bounds__(256) void attn_kern(const bf16* __restrict__ q_enc,
                                                 const bf16* __restrict__ k_enc,
                                                 const bf16* __restrict__ Vt,
                                                 bf16* __restrict__ tmp) {
    int qb = blockIdx.x, h = blockIdx.y, b = blockIdx.z;
    int bh = b * 8 + h;
    __shared__ __align__(16) bf16 Sc[16][SC_STRIDE];
    __shared__ float rowsum[16];
    int t = threadIdx.x;
    int w = t >> 6, l = t & 63;
    int quad = l >> 4, r = l & 15;

    // Q A-fragments (A[m=r][k=quad*8+j]); same for all waves
    const bf16* qrow = q_enc + ((size_t)(bh * 1024 + qb * 16 + r)) * 64 + quad * 8;
    short8 a0 = *(const short8*)(qrow);
    short8 a1 = *(const short8*)(qrow + 32);

    // ---- QK^T: wave w handles k-tiles w*16 .. w*16+15
    const float ascale = 0.125f;  // 1/sqrt(64)
    for (int i = 0; i < 16; ++i) {
        int kt = w * 16 + i;
        const bf16* krow = k_enc + ((size_t)(bh * 1024 + kt * 16 + r)) * 64 + quad * 8;
        short8 b0 = *(const short8*)(krow);
        short8 b1 = *(const short8*)(krow + 32);
        floatx4 c = {0.f, 0.f, 0.f, 0.f};
        c = mfma16(a0, b0, c);
        c = mfma16(a1, b1, c);
        #pragma unroll
        for (int reg = 0; reg < 4; ++reg)
            Sc[quad * 4 + reg][kt * 16 + r] = __float2bfloat16(c[reg] * ascale);
    }
    __syncthreads();

    // ---- softmax: wave w handles rows 4w..4w+3 (exp kept unnormalized in Sc)
    for (int i = 0; i < 4; ++i) {
        int row = w * 4 + i;
        float mx = -1e30f;
        #pragma unroll
        for (int j = 0; j < 16; ++j) mx = fmaxf(mx, b2f(Sc[row][j * 64 + l]));
        #pragma unroll
        for (int off = 32; off; off >>= 1) mx = fmaxf(mx, __shfl_xor(mx, off));
        float sm = 0.f;
        #pragma unroll
        for (int j = 0; j < 16; ++j) {
            float e = __expf(b2f(Sc[row][j * 64 + l]) - mx);
            bf16 eb = __float2bfloat16(e);
            Sc[row][j * 64 + l] = eb;
            sm += b2f(eb);
        }
        #pragma unroll
        for (int off = 32; off; off >>= 1) sm += __shfl_xor(sm, off);
        if (l == 0) rowsum[row] = sm;
    }
    __syncthreads();

    // ---- P@V: wave w owns n-range [w*128, w*128+128) = 8 n-tiles of 16
    floatx4 acc[8];
    #pragma unroll
    for (int nt = 0; nt < 8; ++nt) acc[nt] = (floatx4){0.f, 0.f, 0.f, 0.f};

    const bf16* vb = Vt + ((size_t)(bh * 512 + w * 128 + r)) * 1024 + quad * 8;
    for (int ks = 0; ks < 32; ++ks) {
        short8 a = *(const short8*)(&Sc[r][ks * 32 + quad * 8]);
        #pragma unroll
        for (int nt = 0; nt < 8; ++nt) {
            short8 bf = *(const short8*)(vb + nt * 16384 + ks * 32);
            acc[nt] = mfma16(a, bf, acc[nt]);
        }
    }
    __syncthreads();   // all Sc reads done; reuse Sc space for output staging

    bf16* Ob = &Sc[0][0];
    float inv[4];
    #pragma unroll
    for (int reg = 0; reg < 4; ++reg) inv[reg] = 1.f / rowsum[quad * 4 + reg];
    #pragma unroll
    for (int nt = 0; nt < 8; ++nt)
        #pragma unroll
        for (int reg = 0; reg < 4; ++reg)
            Ob[(quad * 4 + reg) * OB_STRIDE + w * 128 + nt * 16 + r] =
                __float2bfloat16(acc[nt][reg] * inv[reg]);
    __syncthreads();

    // coalesced store: 16 rows x 512 cols bf16 -> tmp[b][q][m][h][d]
    #pragma unroll
    for (int i = 0; i < 4; ++i) {
        int c = i * 256 + t;          // 0..1023 chunks of 8 bf16
        int row = c >> 6, j = c & 63;
        int m = j >> 3, d0 = (j & 7) * 8;
        short8 v = *(const short8*)(Ob + row * OB_STRIDE + j * 8);
        *(short8*)(tmp + ((((size_t)(b * 1024 + qb * 16 + row) * 8 + m) * 8 + h) * 64 + d0)) = v;
    }
}

// ---------------------------------------------------------------------------
// Kernel 5 (MFMA): out_atoms[row, o] = tmp[row, :512] @ Wo_bf[o, :512]
//   rows = (b,s,m) = 32768.  grid: 512 blocks x 64 rows, 256 threads = 4 waves.
//   wave w: rows w*16..w*16+15; 4 n-tiles; K=512 in 16 steps.
//   Then per (b,s): feat = mean_m, new_logw = q_logw + feat @ Ww^T.
// ---------------------------------------------------------------------------
__global__ __launch_bounds__(256) void finalize(const bf16* __restrict__ tmp,
                                                const bf16* __restrict__ Wo_bf,
                                                const float* __restrict__ Ww,
                                                const float* __restrict__ ql,
                                                float* __restrict__ out) {
    __shared__ __align__(16) float Os[64][OS_STRIDE];   // 17.4 KB
    __shared__ float fs[8][64];
    int t = threadIdx.x;
    int w = t >> 6, l = t & 63;
    int quad = l >> 4, r = l & 15;
    size_t rowbase = (size_t)blockIdx.x * 64;

    floatx4 acc[4];
    #pragma unroll
    for (int nt = 0; nt < 4; ++nt) acc[nt] = (floatx4){0.f, 0.f, 0.f, 0.f};

    const bf16* arow = tmp + (rowbase + w * 16 + r) * 512 + quad * 8;
    const bf16* brow = Wo_bf + r * 512 + quad * 8;

    for (int ks = 0; ks < 16; ++ks) {
        short8 a = *(const short8*)(arow + ks * 32);
        #pragma unroll
        for (int nt = 0; nt < 4; ++nt) {
            short8 bb = *(const short8*)(brow + nt * 16 * 512 + ks * 32);
            acc[nt] = mfma16(a, bb, acc[nt]);
        }
    }
    #pragma unroll
    for (int nt = 0; nt < 4; ++nt)
        #pragma unroll
        for (int reg = 0; reg < 4; ++reg)
            Os[w * 16 + quad * 4 + reg][nt * 16 + r] = acc[nt][reg];
    __syncthreads();

    // coalesced out_atoms stores: 64 rows x 64 cols fp32 = 1024 float4
    #pragma unroll
    for (int i = 0; i < 4; ++i) {
        int ch = i * 256 + t;
        int rr = ch >> 4, c4 = (ch & 15) * 4;
        float4 v = *(const float4*)&Os[rr][c4];
        *(float4*)(out + (rowbase + rr) * 64 + c4) = v;
    }

    // feat = mean over m: 8 groups x 64 cols; thread -> (g = t>>5, 2 cols)
    {
        int g = t >> 5, oo = (t & 31) * 2;
        float f0 = 0.f, f1 = 0.f;
        #pragma unroll
        for (int m = 0; m < 8; ++m) {
            f0 += Os[g * 8 + m][oo];
            f1 += Os[g * 8 + m][oo + 1];
        }
        fs[g][oo] = f0 * 0.125f;
        fs[g][oo + 1] = f1 * 0.125f;
    }
    __syncthreads();

    if (t < 64) {
        int g = t >> 3, mm = t & 7;
        size_t x = (size_t)blockIdx.x * 8 + g;   // b*S + s
        float nl = ql[x * 8 + mm];
        #pragma unroll
        for (int o = 0; o < 64; ++o) nl += fs[g][o] * Ww[mm * 64 + o];
        out[(size_t)CB * CS * CM * CD + x * 8 + mm] = nl;
    }
}

// ---------------------------------------------------------------------------
extern "C" void kernel_launch(void* const* d_in, const int* in_sizes, int n_in,
                              void* d_out, int out_size, void* d_ws, size_t ws_size,
                              hipStream_t stream) {
    const float* q_atoms = (const float*)d_in[0];
    const float* q_logw  = (const float*)d_in[1];
    const float* k_atoms = (const float*)d_in[2];
    const float* k_logw  = (const float*)d_in[3];
    const float* v_atoms = (const float*)d_in[4];
    // d_in[5] = v_logw (unused by the reference)
    const float* Wq = (const float*)d_in[6];
    const float* Wk = (const float*)d_in[7];
    const float* Wv = (const float*)d_in[8];
    const float* Wo = (const float*)d_in[9];
    const float* Ww = (const float*)d_in[10];
    const float* freqs = (const float*)d_in[11];

    // ws layout: Fq fp32[16384] | Fk fp32[16384] | q_enc bf16[2097152]
    //   | k_enc bf16[2097152] | Vt bf16[16777216] | tmp bf16[16777216]
    //   | Wo_bf bf16[32768]    (~72.2 MB total)
    float* ws = (float*)d_ws;
    float* Fq = ws;
    float* Fk = ws + 16384;
    bf16* q_enc = (bf16*)(ws + 32768);
    bf16* k_enc = q_enc + 2097152;
    bf16* Vt = k_enc + 2097152;
    bf16* tmp = Vt + 16777216;
    bf16* Wo_bf = tmp + 16777216;
    float* out = (float*)d_out;

    prep_F<<<16, 256, 0, stream>>>(Wq, Wk, freqs, Wo, Fq, Fk, Wo_bf);
    encode<<<CB * CS, 256, 0, stream>>>(q_atoms, q_logw, k_atoms, k_logw,
                                        Fq, Fk, q_enc, k_enc);
    vproj<<<CB * CS / 8, 256, 0, stream>>>(v_atoms, Wv, Vt);
    attn_kern<<<dim3(CS / 16, CH, CB), 256, 0, stream>>>(q_enc, k_enc, Vt, tmp);
    finalize<<<CB * CS / 8, 256, 0, stream>>>(tmp, Wo_bf, Ww, q_logw, out);
}

// Round 5
// 604.771 us; speedup vs baseline: 4.3661x; 1.1948x over previous
//
#include <hip/hip_runtime.h>
#include <hip/hip_bf16.h>

typedef __hip_bfloat16 bf16;
typedef __attribute__((ext_vector_type(8))) short short8;
typedef __attribute__((ext_vector_type(4))) float floatx4;

// Problem constants: B=4, S=1024, M=8, D=64, H=8, NF=32, HD=512
#define CB 4
#define CS 1024
#define CM 8
#define CD 64
#define CH 8
#define CNF 32
#define CHD 512

#define OB_STRIDE 520    // epilogue staging stride (bf16): 16B-aligned rows
#define OS_STRIDE 68     // finalize staging stride (fp32)

__device__ __forceinline__ float b2f(bf16 x) { return __bfloat162float(x); }
__device__ __forceinline__ float us2f(unsigned short u) {
    union { unsigned int i; float f; } v; v.i = ((unsigned int)u) << 16; return v.f;
}
__device__ __forceinline__ floatx4 mfma16(short8 a, short8 b, floatx4 c) {
    return __builtin_amdgcn_mfma_f32_16x16x32_bf16(a, b, c, 0, 0, 0);
}

// ---------------------------------------------------------------------------
// Kernel 1: F[h][e][f] = sum_d W[h*64+d][e] * freqs[h][d][f]  (q and k variants)
// + convert Wo (fp32[64][512]) -> bf16 Wo_bf
// ---------------------------------------------------------------------------
__global__ __launch_bounds__(256) void prep_F(const float* __restrict__ Wq,
                                              const float* __restrict__ Wk,
                                              const float* __restrict__ freqs,
                                              const float* __restrict__ Wo,
                                              float* __restrict__ Fq,
                                              float* __restrict__ Fk,
                                              bf16* __restrict__ Wo_bf) {
    int h = blockIdx.x & 7;
    int which = blockIdx.x >> 3;
    const float* W = which ? Wk : Wq;
    float* F = which ? Fk : Fq;
    int t = threadIdx.x;
    int f = t & 31, e0 = t >> 5;
    for (int ei = 0; ei < 8; ++ei) {
        int e = ei * 8 + e0;
        float acc = 0.f;
        for (int d = 0; d < 64; ++d)
            acc += W[(h * 64 + d) * 64 + e] * freqs[(h * 64 + d) * 32 + f];
        F[h * 2048 + e * 32 + f] = acc;
    }
    int gid = blockIdx.x * 256 + t;
    #pragma unroll
    for (int i = 0; i < 2; ++i) {
        int idx4 = gid * 2 + i;
        float4 v = ((const float4*)Wo)[idx4];
        union { bf16 ob[4]; uint2 u; } pk;
        pk.ob[0] = __float2bfloat16(v.x); pk.ob[1] = __float2bfloat16(v.y);
        pk.ob[2] = __float2bfloat16(v.z); pk.ob[3] = __float2bfloat16(v.w);
        *(uint2*)(Wo_bf + idx4 * 4) = pk.u;
    }
}

// ---------------------------------------------------------------------------
// Kernel 2: q_enc/k_enc[bh][s][f2] (f2<32: cos, f2>=32: sin), softmax-weighted
// over m.  Output bf16.  q side pre-scaled by 1/sqrt(D)=0.125 (attn scale).
// ---------------------------------------------------------------------------
__global__ __launch_bounds__(256) void encode(const float* __restrict__ qa_in,
                                              const float* __restrict__ ql,
                                              const float* __restrict__ ka_in,
                                              const float* __restrict__ kl,
                                              const float* __restrict__ Fq,
                                              const float* __restrict__ Fk,
                                              bf16* __restrict__ q_enc,
                                              bf16* __restrict__ k_enc) {
    int x = blockIdx.x;            // b*S + s
    int b = x >> 10, s = x & 1023;
    __shared__ float atq[8][64];
    __shared__ float atk[8][64];
    __shared__ float lwq[8], lwk[8];
    int t = threadIdx.x;
    for (int i = t; i < 512; i += 256) {
        atq[i >> 6][i & 63] = qa_in[x * 512 + i];
        atk[i >> 6][i & 63] = ka_in[x * 512 + i];
    }
    if (t < 8) lwq[t] = ql[x * 8 + t];
    else if (t < 16) lwk[t - 8] = kl[x * 8 + t - 8];
    __syncthreads();

    int h = t >> 5, f = t & 31;
    const float rs = 0.17677669529663687f;  // 1/sqrt(32)
    int obase = ((b * 8 + h) * 1024 + s) * 64;

    for (int which = 0; which < 2; ++which) {
        const float* F = which ? Fk : Fq;
        const float (*at)[64] = which ? atk : atq;
        const float* lw = which ? lwk : lwq;
        bf16* enc = which ? k_enc : q_enc;
        float oscale = which ? rs : rs * 0.125f;

        float wgt[8];
        float mx = -1e30f;
        #pragma unroll
        for (int m = 0; m < 8; ++m) mx = fmaxf(mx, lw[m]);
        float sm = 0.f;
        #pragma unroll
        for (int m = 0; m < 8; ++m) { wgt[m] = __expf(lw[m] - mx); sm += wgt[m]; }
        float inv = oscale / sm;
        #pragma unroll
        for (int m = 0; m < 8; ++m) wgt[m] *= inv;

        float fr[64];
        #pragma unroll
        for (int e = 0; e < 64; ++e) fr[e] = F[h * 2048 + e * 32 + f];

        float zc = 0.f, zs = 0.f;
        #pragma unroll
        for (int m = 0; m < 8; ++m) {
            float p = 0.f;
            #pragma unroll
            for (int e = 0; e < 64; ++e) p += at[m][e] * fr[e];
            float sv, cv;
            __sincosf(p, &sv, &cv);
            zc += wgt[m] * cv;
            zs += wgt[m] * sv;
        }
        enc[obase + f] = __float2bfloat16(zc);
        enc[obase + 32 + f] = __float2bfloat16(zs);
    }
}

// ---------------------------------------------------------------------------
// Kernel 3: Vt[bh][n][k] (n = m*64+d, k = s), bf16, n-major for MFMA B-frags.
// ---------------------------------------------------------------------------
__global__ __launch_bounds__(256) void vproj(const float* __restrict__ va_in,
                                             const float* __restrict__ Wv,
                                             bf16* __restrict__ Vt) {
    int x = blockIdx.x;
    int b = x >> 7, s0 = (x & 127) * 8;
    __shared__ float atv[8][64][8];   // [m][e][si] 16KB — si contiguous
    int t = threadIdx.x;
    const float* src = va_in + ((size_t)(b * 1024 + s0)) * 512;
    #pragma unroll
    for (int i = 0; i < 4; ++i) {
        int idx4 = t + 256 * i;
        float4 v4 = ((const float4*)src)[idx4];
        int flat = idx4 * 4;              // si*512 + m*64 + e
        int si = flat >> 9, m = (flat >> 6) & 7, e = flat & 63;
        atv[m][e + 0][si] = v4.x;
        atv[m][e + 1][si] = v4.y;
        atv[m][e + 2][si] = v4.z;
        atv[m][e + 3][si] = v4.w;
    }
    __syncthreads();
    for (int rep = 0; rep < 2; ++rep) {
        int c = rep * 256 + t;            // h*64 + d
        int h = c >> 6, d = c & 63;
        float w[64];
        #pragma unroll
        for (int e4 = 0; e4 < 16; ++e4) {
            float4 wv = ((const float4*)(Wv + c * 64))[e4];
            w[e4 * 4 + 0] = wv.x; w[e4 * 4 + 1] = wv.y;
            w[e4 * 4 + 2] = wv.z; w[e4 * 4 + 3] = wv.w;
        }
        for (int m = 0; m < 8; ++m) {
            float acc[8] = {0, 0, 0, 0, 0, 0, 0, 0};
            for (int e = 0; e < 64; ++e) {
                float we = w[e];
                const float4 p0 = *(const float4*)&atv[m][e][0];
                const float4 p1 = *(const float4*)&atv[m][e][4];
                acc[0] += p0.x * we; acc[1] += p0.y * we;
                acc[2] += p0.z * we; acc[3] += p0.w * we;
                acc[4] += p1.x * we; acc[5] += p1.y * we;
                acc[6] += p1.z * we; acc[7] += p1.w * we;
            }
            union { bf16 ob[8]; uint4 u; } pk;
            #pragma unroll
            for (int si = 0; si < 8; ++si) pk.ob[si] = __float2bfloat16(acc[si]);
            *(uint4*)(Vt + ((size_t)((b * 8 + h) * 512 + m * 64 + d)) * 1024 + s0) = pk.u;
        }
    }
}

// ---------------------------------------------------------------------------
// Kernel 4: attention via MFMA.  1024 blocks (XCD-affine bh mapping), 4 waves.
// 32 q-rows/block; Sc[32][1024] bf16 = 64KB LDS, XOR-swizzled 16B chunks.
// QK^T (prefetched K) -> normalized softmax in-place -> P@V (prefetched V,
// 16 MFMA per 8 loads) -> staged coalesced store.
// ---------------------------------------------------------------------------
__global__ __launch_bounds__(256) void attn_kern(const bf16* __restrict__ q_enc,
                                                 const bf16* __restrict__ k_enc,
                                                 const bf16* __restrict__ Vt,
                                                 bf16* __restrict__ tmp) {
    // XCD-affine decode: consecutive-dispatch blocks with same (n%8) share bh
    int n = blockIdx.x;
    int bh = (n & 7) + 8 * (n >> 8);     // n>>8 = n/256 in [0,4)
    int qb = (n >> 3) & 31;
    int b = bh >> 3, h = bh & 7;

    __shared__ __align__(16) bf16 Sc[32 * 1024];   // 64KB
    int t = threadIdx.x;
    int w = t >> 6, l = t & 63;
    int quad = l >> 4, r = l & 15;
    int k7 = r & 7;

    // ---- Phase 1: QK^T  (q pre-scaled by 1/sqrt(D) in encode)
    const bf16* qbase = q_enc + ((size_t)(bh * 1024 + qb * 32 + r)) * 64 + quad * 8;
    short8 a0 = *(const short8*)(qbase);
    short8 a1 = *(const short8*)(qbase + 32);
    short8 a2 = *(const short8*)(qbase + 16 * 64);
    short8 a3 = *(const short8*)(qbase + 16 * 64 + 32);

    const bf16* kbase = k_enc + ((size_t)(bh * 1024 + r)) * 64 + quad * 8;
    short8 nb0 = *(const short8*)(kbase + (size_t)(w * 16) * 1024);
    short8 nb1 = *(const short8*)(kbase + (size_t)(w * 16) * 1024 + 32);

    for (int i = 0; i < 16; ++i) {
        short8 b0 = nb0, b1 = nb1;
        if (i < 15) {
            nb0 = *(const short8*)(kbase + (size_t)(w * 16 + i + 1) * 1024);
            nb1 = *(const short8*)(kbase + (size_t)(w * 16 + i + 1) * 1024 + 32);
        }
        floatx4 c0 = {0.f, 0.f, 0.f, 0.f}, c1 = {0.f, 0.f, 0.f, 0.f};
        c0 = mfma16(a0, b0, c0); c0 = mfma16(a1, b1, c0);
        c1 = mfma16(a2, b0, c1); c1 = mfma16(a3, b1, c1);
        int kt = w * 16 + i;
        int chunkbase = kt * 2 + (r >> 3);
        int off = r & 7;
        #pragma unroll
        for (int reg = 0; reg < 4; ++reg) {
            int row0 = quad * 4 + reg;
            int pc = ((chunkbase ^ (row0 & 7)) << 3) + off;
            Sc[row0 * 1024 + pc] = __float2bfloat16(c0[reg]);
            Sc[(row0 + 16) * 1024 + pc] = __float2bfloat16(c1[reg]);
        }
    }
    __syncthreads();

    // ---- Phase 2: softmax, normalized in place (wave w: rows w*8..w*8+7)
    for (int i = 0; i < 8; ++i) {
        int row = w * 8 + i;
        int key = row & 7;
        bf16* rowp = Sc + row * 1024;
        int p0 = ((2 * l) ^ key) << 3;
        int p1 = ((2 * l + 1) ^ key) << 3;
        union { short8 s; unsigned short u[8]; } v0, v1;
        v0.s = *(const short8*)(rowp + p0);
        v1.s = *(const short8*)(rowp + p1);
        float f[16];
        #pragma unroll
        for (int j = 0; j < 8; ++j) { f[j] = us2f(v0.u[j]); f[8 + j] = us2f(v1.u[j]); }
        float mx = -1e30f;
        #pragma unroll
        for (int j = 0; j < 16; ++j) mx = fmaxf(mx, f[j]);
        #pragma unroll
        for (int off = 32; off; off >>= 1) mx = fmaxf(mx, __shfl_xor(mx, off));
        float sm = 0.f;
        #pragma unroll
        for (int j = 0; j < 16; ++j) { f[j] = __expf(f[j] - mx); sm += f[j]; }
        #pragma unroll
        for (int off = 32; off; off >>= 1) sm += __shfl_xor(sm, off);
        float inv = 1.f / sm;
        #pragma unroll
        for (int j = 0; j < 8; ++j) {
            v0.u[j] = (unsigned short)(__bfloat16_as_ushort(__float2bfloat16(f[j] * inv)));
            v1.u[j] = (unsigned short)(__bfloat16_as_ushort(__float2bfloat16(f[8 + j] * inv)));
        }
        *(short8*)(rowp + p0) = v0.s;
        *(short8*)(rowp + p1) = v1.s;
    }
    __syncthreads();

    // ---- Phase 3: P@V.  wave w: n-cols [w*128, w*128+128), both 16-row tiles.
    floatx4 acc0[8], acc1[8];
    #pragma unroll
    for (int nt = 0; nt < 8; ++nt) {
        acc0[nt] = (floatx4){0.f, 0.f, 0.f, 0.f};
        acc1[nt] = (floatx4){0.f, 0.f, 0.f, 0.f};
    }
    const bf16* vbase = Vt + ((size_t)(bh * 512 + w * 128 + r)) * 1024 + quad * 8;
    short8 cur[8], nxt[8];
    #pragma unroll
    for (int nt = 0; nt < 8; ++nt) nxt[nt] = *(const short8*)(vbase + nt * 16384);

    for (int ks = 0; ks < 32; ++ks) {
        #pragma unroll
        for (int nt = 0; nt < 8; ++nt) cur[nt] = nxt[nt];
        if (ks < 31) {
            #pragma unroll
            for (int nt = 0; nt < 8; ++nt)
                nxt[nt] = *(const short8*)(vbase + nt * 16384 + (ks + 1) * 32);
        }
        int pc = (((ks * 4 + quad) ^ k7) << 3);
        short8 pa0 = *(const short8*)(Sc + r * 1024 + pc);
        short8 pa1 = *(const short8*)(Sc + (16 + r) * 1024 + pc);
        #pragma unroll
        for (int nt = 0; nt < 8; ++nt) {
            acc0[nt] = mfma16(pa0, cur[nt], acc0[nt]);
            acc1[nt] = mfma16(pa1, cur[nt], acc1[nt]);
        }
    }
    __syncthreads();   // all Sc reads done; reuse for output staging

    bf16* Ob = Sc;
    #pragma unroll
    for (int nt = 0; nt < 8; ++nt)
        #pragma unroll
        for (int reg = 0; reg < 4; ++reg) {
            int col = w * 128 + nt * 16 + r;
            Ob[(quad * 4 + reg) * OB_STRIDE + col] = __float2bfloat16(acc0[nt][reg]);
            Ob[(quad * 4 + reg + 16) * OB_STRIDE + col] = __float2bfloat16(acc1[nt][reg]);
        }
    __syncthreads();

    // coalesced store: 32 rows x 512 cols bf16 -> tmp[b][q][m][h][d]
    #pragma unroll
    for (int i = 0; i < 8; ++i) {
        int c = i * 256 + t;          // 0..2047 chunks of 8 bf16
        int row = c >> 6, j = c & 63;
        int m = j >> 3, d0 = (j & 7) * 8;
        short8 v = *(const short8*)(Ob + row * OB_STRIDE + j * 8);
        *(short8*)(tmp + ((((size_t)(b * 1024 + qb * 32 + row) * 8 + m) * 8 + h) * 64 + d0)) = v;
    }
}

// ---------------------------------------------------------------------------
// Kernel 5 (MFMA): out_atoms[row, o] = tmp[row, :512] @ Wo_bf[o, :512]
// ---------------------------------------------------------------------------
__global__ __launch_bounds__(256) void finalize(const bf16* __restrict__ tmp,
                                                const bf16* __restrict__ Wo_bf,
                                                const float* __restrict__ Ww,
                                                const float* __restrict__ ql,
                                                float* __restrict__ out) {
    __shared__ __align__(16) float Os[64][OS_STRIDE];   // 17.4 KB
    __shared__ float fs[8][64];
    int t = threadIdx.x;
    int w = t >> 6, l = t & 63;
    int quad = l >> 4, r = l & 15;
    size_t rowbase = (size_t)blockIdx.x * 64;

    floatx4 acc[4];
    #pragma unroll
    for (int nt = 0; nt < 4; ++nt) acc[nt] = (floatx4){0.f, 0.f, 0.f, 0.f};

    const bf16* arow = tmp + (rowbase + w * 16 + r) * 512 + quad * 8;
    const bf16* brow = Wo_bf + r * 512 + quad * 8;

    for (int ks = 0; ks < 16; ++ks) {
        short8 a = *(const short8*)(arow + ks * 32);
        #pragma unroll
        for (int nt = 0; nt < 4; ++nt) {
            short8 bb = *(const short8*)(brow + nt * 16 * 512 + ks * 32);
            acc[nt] = mfma16(a, bb, acc[nt]);
        }
    }
    #pragma unroll
    for (int nt = 0; nt < 4; ++nt)
        #pragma unroll
        for (int reg = 0; reg < 4; ++reg)
            Os[w * 16 + quad * 4 + reg][nt * 16 + r] = acc[nt][reg];
    __syncthreads();

    #pragma unroll
    for (int i = 0; i < 4; ++i) {
        int ch = i * 256 + t;
        int rr = ch >> 4, c4 = (ch & 15) * 4;
        float4 v = *(const float4*)&Os[rr][c4];
        *(float4*)(out + (rowbase + rr) * 64 + c4) = v;
    }

    {
        int g = t >> 5, oo = (t & 31) * 2;
        float f0 = 0.f, f1 = 0.f;
        #pragma unroll
        for (int m = 0; m < 8; ++m) {
            f0 += Os[g * 8 + m][oo];
            f1 += Os[g * 8 + m][oo + 1];
        }
        fs[g][oo] = f0 * 0.125f;
        fs[g][oo + 1] = f1 * 0.125f;
    }
    __syncthreads();

    if (t < 64) {
        int g = t >> 3, mm = t & 7;
        size_t x = (size_t)blockIdx.x * 8 + g;   // b*S + s
        float nl = ql[x * 8 + mm];
        #pragma unroll
        for (int o = 0; o < 64; ++o) nl += fs[g][o] * Ww[mm * 64 + o];
        out[(size_t)CB * CS * CM * CD + x * 8 + mm] = nl;
    }
}

// ---------------------------------------------------------------------------
extern "C" void kernel_launch(void* const* d_in, const int* in_sizes, int n_in,
                              void* d_out, int out_size, void* d_ws, size_t ws_size,
                              hipStream_t stream) {
    const float* q_atoms = (const float*)d_in[0];
    const float* q_logw  = (const float*)d_in[1];
    const float* k_atoms = (const float*)d_in[2];
    const float* k_logw  = (const float*)d_in[3];
    const float* v_atoms = (const float*)d_in[4];
    // d_in[5] = v_logw (unused by the reference)
    const float* Wq = (const float*)d_in[6];
    const float* Wk = (const float*)d_in[7];
    const float* Wv = (const float*)d_in[8];
    const float* Wo = (const float*)d_in[9];
    const float* Ww = (const float*)d_in[10];
    const float* freqs = (const float*)d_in[11];

    // ws layout: Fq fp32[16384] | Fk fp32[16384] | q_enc bf16[2097152]
    //   | k_enc bf16[2097152] | Vt bf16[16777216] | tmp bf16[16777216]
    //   | Wo_bf bf16[32768]
    float* ws = (float*)d_ws;
    float* Fq = ws;
    float* Fk = ws + 16384;
    bf16* q_enc = (bf16*)(ws + 32768);
    bf16* k_enc = q_enc + 2097152;
    bf16* Vt = k_enc + 2097152;
    bf16* tmp = Vt + 16777216;
    bf16* Wo_bf = tmp + 16777216;
    float* out = (float*)d_out;

    prep_F<<<16, 256, 0, stream>>>(Wq, Wk, freqs, Wo, Fq, Fk, Wo_bf);
    encode<<<CB * CS, 256, 0, stream>>>(q_atoms, q_logw, k_atoms, k_logw,
                                        Fq, Fk, q_enc, k_enc);
    vproj<<<CB * CS / 8, 256, 0, stream>>>(v_atoms, Wv, Vt);
    attn_kern<<<1024, 256, 0, stream>>>(q_enc, k_enc, Vt, tmp);
    finalize<<<CB * CS / 8, 256, 0, stream>>>(tmp, Wo_bf, Ww, q_logw, out);
}

// Round 6
// 381.427 us; speedup vs baseline: 6.9226x; 1.5855x over previous
//
#include <hip/hip_runtime.h>
#include <hip/hip_bf16.h>

typedef __hip_bfloat16 bf16;
typedef __attribute__((ext_vector_type(8))) short short8;
typedef __attribute__((ext_vector_type(4))) float floatx4;

// Problem constants: B=4, S=1024, M=8, D=64, H=8, NF=32, HD=512
#define CB 4
#define CS 1024
#define CM 8
#define CD 64
#define CH 8
#define CNF 32
#define CHD 512

#define OB_STRIDE 520    // attn epilogue staging stride (bf16): 16B-aligned rows
#define OS_STRIDE 68     // finalize staging stride (fp32)

__device__ __forceinline__ float b2f(bf16 x) { return __bfloat162float(x); }
__device__ __forceinline__ float us2f(unsigned short u) {
    union { unsigned int i; float f; } v; v.i = ((unsigned int)u) << 16; return v.f;
}
__device__ __forceinline__ floatx4 mfma16(short8 a, short8 b, floatx4 c) {
    return __builtin_amdgcn_mfma_f32_16x16x32_bf16(a, b, c, 0, 0, 0);
}
__device__ __forceinline__ short8 pack8(float4 x, float4 y) {
    union { short8 s; bf16 b[8]; } u;
    u.b[0] = __float2bfloat16(x.x); u.b[1] = __float2bfloat16(x.y);
    u.b[2] = __float2bfloat16(x.z); u.b[3] = __float2bfloat16(x.w);
    u.b[4] = __float2bfloat16(y.x); u.b[5] = __float2bfloat16(y.y);
    u.b[6] = __float2bfloat16(y.z); u.b[7] = __float2bfloat16(y.w);
    return u.s;
}

// ---------------------------------------------------------------------------
// Kernel 1: Fb[which][n=h*32+f][e] (bf16, n-major MFMA B-layout)
//   = sum_d W[h*64+d][e] * freqs[h][d][f];  + convert Wo -> bf16.
// grid: 16 blocks (which*8 + h), 256 threads
// ---------------------------------------------------------------------------
__global__ __launch_bounds__(256) void prep_F(const float* __restrict__ Wq,
                                              const float* __restrict__ Wk,
                                              const float* __restrict__ freqs,
                                              const float* __restrict__ Wo,
                                              bf16* __restrict__ Fqb,
                                              bf16* __restrict__ Fkb,
                                              bf16* __restrict__ Wo_bf) {
    int h = blockIdx.x & 7;
    int which = blockIdx.x >> 3;
    const float* W = which ? Wk : Wq;
    bf16* Fb = which ? Fkb : Fqb;
    int t = threadIdx.x;
    int f = t & 31, e0 = t >> 5;
    for (int ei = 0; ei < 8; ++ei) {
        int e = ei * 8 + e0;
        float acc = 0.f;
        for (int d = 0; d < 64; ++d)
            acc += W[(h * 64 + d) * 64 + e] * freqs[(h * 64 + d) * 32 + f];
        Fb[(h * 32 + f) * 64 + e] = __float2bfloat16(acc);
    }
    int gid = blockIdx.x * 256 + t;
    #pragma unroll
    for (int i = 0; i < 2; ++i) {
        int idx4 = gid * 2 + i;
        float4 v = ((const float4*)Wo)[idx4];
        union { bf16 ob[4]; uint2 u; } pk;
        pk.ob[0] = __float2bfloat16(v.x); pk.ob[1] = __float2bfloat16(v.y);
        pk.ob[2] = __float2bfloat16(v.z); pk.ob[3] = __float2bfloat16(v.w);
        *(uint2*)(Wo_bf + idx4 * 4) = pk.u;
    }
}

// ---------------------------------------------------------------------------
// Kernel 2 (MFMA): encode.  p[(b,s,m),(h,f)] = atoms @ F^T as [32,64]@[64,256]
// per block (4 (b,s) x 8 m rows), then sincos + softmax-weighted m-reduction.
// grid: 1024 blocks, 256 threads = 4 waves.
// wave w: row-tile tw=w&1 (16 rows), n-tiles nb=(w>>1)*8 .. +8.
// q side pre-scaled by 1/sqrt(D)=0.125 (attn scale folded into weights).
// ---------------------------------------------------------------------------
__global__ __launch_bounds__(256) void encode(const float* __restrict__ qa_in,
                                              const float* __restrict__ ql,
                                              const float* __restrict__ ka_in,
                                              const float* __restrict__ kl,
                                              const bf16* __restrict__ Fqb,
                                              const bf16* __restrict__ Fkb,
                                              bf16* __restrict__ q_enc,
                                              bf16* __restrict__ k_enc) {
    int blk = blockIdx.x;
    int xbase = blk * 4;             // 4 (b,s) groups
    int b = xbase >> 10, s0 = xbase & 1023;
    __shared__ float wgtL[2][32];
    __shared__ __align__(16) bf16 zL[2 * 4 * 8 * 64];   // 8KB
    int t = threadIdx.x;
    int w = t >> 6, l = t & 63;
    int quad = l >> 4, r = l & 15;
    int tw = w & 1, nb = (w >> 1) * 8;

    // softmax weights over m for each (which, si, m); rff/attn scales folded in
    if (t < 64) {
        int which = t >> 5, row = t & 31;
        int si = row >> 3, m = row & 7;
        const float* lwp = (which ? kl : ql) + (size_t)(xbase + si) * 8;
        float lw[8]; float mx = -1e30f;
        #pragma unroll
        for (int j = 0; j < 8; ++j) { lw[j] = lwp[j]; mx = fmaxf(mx, lw[j]); }
        float sm = 0.f;
        #pragma unroll
        for (int j = 0; j < 8; ++j) sm += __expf(lw[j] - mx);
        const float rs = 0.17677669529663687f;  // 1/sqrt(32)
        float osc = which ? rs : rs * 0.125f;
        wgtL[which][row] = __expf(lw[m] - mx) * (osc / sm);
    }
    __syncthreads();

    for (int which = 0; which < 2; ++which) {
        const float* at = which ? ka_in : qa_in;
        const bf16* Fb = which ? Fkb : Fqb;

        // A-fragments: atom row = blk*32 + tw*16 + r, e = quad*8.. (+32)
        const float* arow = at + ((size_t)(blk * 32 + tw * 16 + r)) * 64 + quad * 8;
        float4 af0 = *(const float4*)(arow);
        float4 af1 = *(const float4*)(arow + 4);
        float4 af2 = *(const float4*)(arow + 32);
        float4 af3 = *(const float4*)(arow + 36);
        short8 a0 = pack8(af0, af1);
        short8 a1 = pack8(af2, af3);

        floatx4 acc[8];
        #pragma unroll
        for (int nt = 0; nt < 8; ++nt) {
            int n = (nb + nt) * 16 + r;
            short8 b0 = *(const short8*)(Fb + n * 64 + quad * 8);
            short8 b1 = *(const short8*)(Fb + n * 64 + quad * 8 + 32);
            floatx4 c = {0.f, 0.f, 0.f, 0.f};
            c = mfma16(a0, b0, c);
            c = mfma16(a1, b1, c);
            acc[nt] = c;
        }

        float wv[4];
        #pragma unroll
        for (int reg = 0; reg < 4; ++reg)
            wv[reg] = wgtL[which][tw * 16 + quad * 4 + reg];

        int si = tw * 2 + (quad >> 1);
        int iss = quad & 1;
        #pragma unroll
        for (int nt = 0; nt < 8; ++nt) {
            int n = (nb + nt) * 16 + r;
            int h = n >> 5, f = n & 31;
            float zc = 0.f, zs = 0.f;
            #pragma unroll
            for (int reg = 0; reg < 4; ++reg) {
                float sv, cv;
                __sincosf(acc[nt][reg], &sv, &cv);
                zc += wv[reg] * cv;
                zs += wv[reg] * sv;
            }
            // combine the two quads covering this si (rows 0..7 / 8..15)
            zc += __shfl_xor(zc, 16);
            zs += __shfl_xor(zs, 16);
            float val = iss ? zs : zc;
            zL[((which * 4 + si) * 8 + h) * 64 + f + 32 * iss] = __float2bfloat16(val);
        }
    }
    __syncthreads();

    // coalesced output: 128 rows (which,si,h) x 64 f2 -> enc[bh][s][f2]
    #pragma unroll
    for (int rep = 0; rep < 2; ++rep) {
        int idx = rep * 256 + t;             // 0..511 chunks of 8 bf16
        int row = idx >> 3, c = idx & 7;     // row = which*32 + si*8 + h
        int which = row >> 5, si = (row >> 3) & 3, h = row & 7;
        bf16* enc = which ? k_enc : q_enc;
        short8 v = *(const short8*)(zL + row * 64 + c * 8);
        *(short8*)(enc + ((size_t)((b * 8 + h) * 1024 + s0 + si)) * 64 + c * 8) = v;
    }
}

// ---------------------------------------------------------------------------
// Kernel 3: Vt[bh][n][k] (n = m*64+d, k = s), bf16, n-major for MFMA B-frags.
// ---------------------------------------------------------------------------
__global__ __launch_bounds__(256) void vproj(const float* __restrict__ va_in,
                                             const float* __restrict__ Wv,
                                             bf16* __restrict__ Vt) {
    int x = blockIdx.x;
    int b = x >> 7, s0 = (x & 127) * 8;
    __shared__ float atv[8][64][8];   // [m][e][si] 16KB — si contiguous
    int t = threadIdx.x;
    const float* src = va_in + ((size_t)(b * 1024 + s0)) * 512;
    #pragma unroll
    for (int i = 0; i < 4; ++i) {
        int idx4 = t + 256 * i;
        float4 v4 = ((const float4*)src)[idx4];
        int flat = idx4 * 4;              // si*512 + m*64 + e
        int si = flat >> 9, m = (flat >> 6) & 7, e = flat & 63;
        atv[m][e + 0][si] = v4.x;
        atv[m][e + 1][si] = v4.y;
        atv[m][e + 2][si] = v4.z;
        atv[m][e + 3][si] = v4.w;
    }
    __syncthreads();
    for (int rep = 0; rep < 2; ++rep) {
        int c = rep * 256 + t;            // h*64 + d
        int h = c >> 6, d = c & 63;
        float w[64];
        #pragma unroll
        for (int e4 = 0; e4 < 16; ++e4) {
            float4 wv = ((const float4*)(Wv + c * 64))[e4];
            w[e4 * 4 + 0] = wv.x; w[e4 * 4 + 1] = wv.y;
            w[e4 * 4 + 2] = wv.z; w[e4 * 4 + 3] = wv.w;
        }
        for (int m = 0; m < 8; ++m) {
            float acc[8] = {0, 0, 0, 0, 0, 0, 0, 0};
            for (int e = 0; e < 64; ++e) {
                float we = w[e];
                const float4 p0 = *(const float4*)&atv[m][e][0];
                const float4 p1 = *(const float4*)&atv[m][e][4];
                acc[0] += p0.x * we; acc[1] += p0.y * we;
                acc[2] += p0.z * we; acc[3] += p0.w * we;
                acc[4] += p1.x * we; acc[5] += p1.y * we;
                acc[6] += p1.z * we; acc[7] += p1.w * we;
            }
            union { bf16 ob[8]; uint4 u; } pk;
            #pragma unroll
            for (int si = 0; si < 8; ++si) pk.ob[si] = __float2bfloat16(acc[si]);
            *(uint4*)(Vt + ((size_t)((b * 8 + h) * 512 + m * 64 + d)) * 1024 + s0) = pk.u;
        }
    }
}

// ---------------------------------------------------------------------------
// Kernel 4: attention via MFMA.  1024 blocks (XCD-affine bh mapping), 4 waves.
// 32 q-rows/block; Sc[32][1024] bf16 = 64KB LDS, XOR-swizzled 16B chunks.
// ---------------------------------------------------------------------------
__global__ __launch_bounds__(256) void attn_kern(const bf16* __restrict__ q_enc,
                                                 const bf16* __restrict__ k_enc,
                                                 const bf16* __restrict__ Vt,
                                                 bf16* __restrict__ tmp) {
    int n = blockIdx.x;
    int bh = (n & 7) + 8 * (n >> 8);
    int qb = (n >> 3) & 31;
    int b = bh >> 3, h = bh & 7;

    __shared__ __align__(16) bf16 Sc[32 * 1024];   // 64KB
    int t = threadIdx.x;
    int w = t >> 6, l = t & 63;
    int quad = l >> 4, r = l & 15;
    int k7 = r & 7;

    // ---- Phase 1: QK^T  (q pre-scaled by 1/sqrt(D) in encode)
    const bf16* qbase = q_enc + ((size_t)(bh * 1024 + qb * 32 + r)) * 64 + quad * 8;
    short8 a0 = *(const short8*)(qbase);
    short8 a1 = *(const short8*)(qbase + 32);
    short8 a2 = *(const short8*)(qbase + 16 * 64);
    short8 a3 = *(const short8*)(qbase + 16 * 64 + 32);

    const bf16* kbase = k_enc + ((size_t)(bh * 1024 + r)) * 64 + quad * 8;
    short8 nb0 = *(const short8*)(kbase + (size_t)(w * 16) * 1024);
    short8 nb1 = *(const short8*)(kbase + (size_t)(w * 16) * 1024 + 32);

    for (int i = 0; i < 16; ++i) {
        short8 b0 = nb0, b1 = nb1;
        if (i < 15) {
            nb0 = *(const short8*)(kbase + (size_t)(w * 16 + i + 1) * 1024);
            nb1 = *(const short8*)(kbase + (size_t)(w * 16 + i + 1) * 1024 + 32);
        }
        floatx4 c0 = {0.f, 0.f, 0.f, 0.f}, c1 = {0.f, 0.f, 0.f, 0.f};
        c0 = mfma16(a0, b0, c0); c0 = mfma16(a1, b1, c0);
        c1 = mfma16(a2, b0, c1); c1 = mfma16(a3, b1, c1);
        int kt = w * 16 + i;
        int chunkbase = kt * 2 + (r >> 3);
        int off = r & 7;
        #pragma unroll
        for (int reg = 0; reg < 4; ++reg) {
            int row0 = quad * 4 + reg;
            int pc = ((chunkbase ^ (row0 & 7)) << 3) + off;
            Sc[row0 * 1024 + pc] = __float2bfloat16(c0[reg]);
            Sc[(row0 + 16) * 1024 + pc] = __float2bfloat16(c1[reg]);
        }
    }
    __syncthreads();

    // ---- Phase 2: softmax, normalized in place (wave w: rows w*8..w*8+7)
    for (int i = 0; i < 8; ++i) {
        int row = w * 8 + i;
        int key = row & 7;
        bf16* rowp = Sc + row * 1024;
        int p0 = ((2 * l) ^ key) << 3;
        int p1 = ((2 * l + 1) ^ key) << 3;
        union { short8 s; unsigned short u[8]; } v0, v1;
        v0.s = *(const short8*)(rowp + p0);
        v1.s = *(const short8*)(rowp + p1);
        float f[16];
        #pragma unroll
        for (int j = 0; j < 8; ++j) { f[j] = us2f(v0.u[j]); f[8 + j] = us2f(v1.u[j]); }
        float mx = -1e30f;
        #pragma unroll
        for (int j = 0; j < 16; ++j) mx = fmaxf(mx, f[j]);
        #pragma unroll
        for (int off = 32; off; off >>= 1) mx = fmaxf(mx, __shfl_xor(mx, off));
        float sm = 0.f;
        #pragma unroll
        for (int j = 0; j < 16; ++j) { f[j] = __expf(f[j] - mx); sm += f[j]; }
        #pragma unroll
        for (int off = 32; off; off >>= 1) sm += __shfl_xor(sm, off);
        float inv = 1.f / sm;
        #pragma unroll
        for (int j = 0; j < 8; ++j) {
            v0.u[j] = (unsigned short)(__bfloat16_as_ushort(__float2bfloat16(f[j] * inv)));
            v1.u[j] = (unsigned short)(__bfloat16_as_ushort(__float2bfloat16(f[8 + j] * inv)));
        }
        *(short8*)(rowp + p0) = v0.s;
        *(short8*)(rowp + p1) = v1.s;
    }
    __syncthreads();

    // ---- Phase 3: P@V.  wave w: n-cols [w*128, w*128+128), both 16-row tiles.
    floatx4 acc0[8], acc1[8];
    #pragma unroll
    for (int nt = 0; nt < 8; ++nt) {
        acc0[nt] = (floatx4){0.f, 0.f, 0.f, 0.f};
        acc1[nt] = (floatx4){0.f, 0.f, 0.f, 0.f};
    }
    const bf16* vbase = Vt + ((size_t)(bh * 512 + w * 128 + r)) * 1024 + quad * 8;
    short8 cur[8], nxt[8];
    #pragma unroll
    for (int nt = 0; nt < 8; ++nt) nxt[nt] = *(const short8*)(vbase + nt * 16384);

    for (int ks = 0; ks < 32; ++ks) {
        #pragma unroll
        for (int nt = 0; nt < 8; ++nt) cur[nt] = nxt[nt];
        if (ks < 31) {
            #pragma unroll
            for (int nt = 0; nt < 8; ++nt)
                nxt[nt] = *(const short8*)(vbase + nt * 16384 + (ks + 1) * 32);
        }
        int pc = (((ks * 4 + quad) ^ k7) << 3);
        short8 pa0 = *(const short8*)(Sc + r * 1024 + pc);
        short8 pa1 = *(const short8*)(Sc + (16 + r) * 1024 + pc);
        #pragma unroll
        for (int nt = 0; nt < 8; ++nt) {
            acc0[nt] = mfma16(pa0, cur[nt], acc0[nt]);
            acc1[nt] = mfma16(pa1, cur[nt], acc1[nt]);
        }
    }
    __syncthreads();   // all Sc reads done; reuse for output staging

    bf16* Ob = Sc;
    #pragma unroll
    for (int nt = 0; nt < 8; ++nt)
        #pragma unroll
        for (int reg = 0; reg < 4; ++reg) {
            int col = w * 128 + nt * 16 + r;
            Ob[(quad * 4 + reg) * OB_STRIDE + col] = __float2bfloat16(acc0[nt][reg]);
            Ob[(quad * 4 + reg + 16) * OB_STRIDE + col] = __float2bfloat16(acc1[nt][reg]);
        }
    __syncthreads();

    // coalesced store: 32 rows x 512 cols bf16 -> tmp[b][q][m][h][d]
    #pragma unroll
    for (int i = 0; i < 8; ++i) {
        int c = i * 256 + t;
        int row = c >> 6, j = c & 63;
        int m = j >> 3, d0 = (j & 7) * 8;
        short8 v = *(const short8*)(Ob + row * OB_STRIDE + j * 8);
        *(short8*)(tmp + ((((size_t)(b * 1024 + qb * 32 + row) * 8 + m) * 8 + h) * 64 + d0)) = v;
    }
}

// ---------------------------------------------------------------------------
// Kernel 5 (MFMA): out_atoms[row, o] = tmp[row, :512] @ Wo_bf[o, :512]
// ---------------------------------------------------------------------------
__global__ __launch_bounds__(256) void finalize(const bf16* __restrict__ tmp,
                                                const bf16* __restrict__ Wo_bf,
                                                const float* __restrict__ Ww,
                                                const float* __restrict__ ql,
                                                float* __restrict__ out) {
    __shared__ __align__(16) float Os[64][OS_STRIDE];   // 17.4 KB
    __shared__ float fs[8][64];
    int t = threadIdx.x;
    int w = t >> 6, l = t & 63;
    int quad = l >> 4, r = l & 15;
    size_t rowbase = (size_t)blockIdx.x * 64;

    floatx4 acc[4];
    #pragma unroll
    for (int nt = 0; nt < 4; ++nt) acc[nt] = (floatx4){0.f, 0.f, 0.f, 0.f};

    const bf16* arow = tmp + (rowbase + w * 16 + r) * 512 + quad * 8;
    const bf16* brow = Wo_bf + r * 512 + quad * 8;

    for (int ks = 0; ks < 16; ++ks) {
        short8 a = *(const short8*)(arow + ks * 32);
        #pragma unroll
        for (int nt = 0; nt < 4; ++nt) {
            short8 bb = *(const short8*)(brow + nt * 16 * 512 + ks * 32);
            acc[nt] = mfma16(a, bb, acc[nt]);
        }
    }
    #pragma unroll
    for (int nt = 0; nt < 4; ++nt)
        #pragma unroll
        for (int reg = 0; reg < 4; ++reg)
            Os[w * 16 + quad * 4 + reg][nt * 16 + r] = acc[nt][reg];
    __syncthreads();

    #pragma unroll
    for (int i = 0; i < 4; ++i) {
        int ch = i * 256 + t;
        int rr = ch >> 4, c4 = (ch & 15) * 4;
        float4 v = *(const float4*)&Os[rr][c4];
        *(float4*)(out + (rowbase + rr) * 64 + c4) = v;
    }

    {
        int g = t >> 5, oo = (t & 31) * 2;
        float f0 = 0.f, f1 = 0.f;
        #pragma unroll
        for (int m = 0; m < 8; ++m) {
            f0 += Os[g * 8 + m][oo];
            f1 += Os[g * 8 + m][oo + 1];
        }
        fs[g][oo] = f0 * 0.125f;
        fs[g][oo + 1] = f1 * 0.125f;
    }
    __syncthreads();

    if (t < 64) {
        int g = t >> 3, mm = t & 7;
        size_t x = (size_t)blockIdx.x * 8 + g;   // b*S + s
        float nl = ql[x * 8 + mm];
        #pragma unroll
        for (int o = 0; o < 64; ++o) nl += fs[g][o] * Ww[mm * 64 + o];
        out[(size_t)CB * CS * CM * CD + x * 8 + mm] = nl;
    }
}

// ---------------------------------------------------------------------------
extern "C" void kernel_launch(void* const* d_in, const int* in_sizes, int n_in,
                              void* d_out, int out_size, void* d_ws, size_t ws_size,
                              hipStream_t stream) {
    const float* q_atoms = (const float*)d_in[0];
    const float* q_logw  = (const float*)d_in[1];
    const float* k_atoms = (const float*)d_in[2];
    const float* k_logw  = (const float*)d_in[3];
    const float* v_atoms = (const float*)d_in[4];
    // d_in[5] = v_logw (unused by the reference)
    const float* Wq = (const float*)d_in[6];
    const float* Wk = (const float*)d_in[7];
    const float* Wv = (const float*)d_in[8];
    const float* Wo = (const float*)d_in[9];
    const float* Ww = (const float*)d_in[10];
    const float* freqs = (const float*)d_in[11];

    // ws layout (all bf16): Fqb[16384] | Fkb[16384] | q_enc[2097152]
    //   | k_enc[2097152] | Vt[16777216] | tmp[16777216] | Wo_bf[32768]
    bf16* Fqb = (bf16*)d_ws;
    bf16* Fkb = Fqb + 16384;
    bf16* q_enc = Fkb + 16384;
    bf16* k_enc = q_enc + 2097152;
    bf16* Vt = k_enc + 2097152;
    bf16* tmp = Vt + 16777216;
    bf16* Wo_bf = tmp + 16777216;
    float* out = (float*)d_out;

    prep_F<<<16, 256, 0, stream>>>(Wq, Wk, freqs, Wo, Fqb, Fkb, Wo_bf);
    encode<<<1024, 256, 0, stream>>>(q_atoms, q_logw, k_atoms, k_logw,
                                     Fqb, Fkb, q_enc, k_enc);
    vproj<<<CB * CS / 8, 256, 0, stream>>>(v_atoms, Wv, Vt);
    attn_kern<<<1024, 256, 0, stream>>>(q_enc, k_enc, Vt, tmp);
    finalize<<<CB * CS / 8, 256, 0, stream>>>(tmp, Wo_bf, Ww, q_logw, out);
}